// Round 4
// baseline (928.414 us; speedup 1.0000x reference)
//
#include <hip/hip_runtime.h>

#define SHFL16(v, k) __shfl((v), (k), 16)
#define FENCE() asm volatile("" ::: "memory")

// per-item LDS layout (dwords). Matrix row stride 20 -> wide row writes are
// <=2-way bank conflicts (free). Item stride 840 == 8 (mod 32): the wave's 4
// lockstep groups land on disjoint bank quartets for uniform b128 broadcasts.
#define STR     840
#define OFF_M1    0   // P -> Pp -> Pn        (15 rows x 20)
#define OFF_M2  300   // A -> IKC             (15 rows x 20)
#define OFF_C   600   // C                    (6 rows x 16)
#define OFF_S4  696   // B -> PpCt -> K       (15 rows x 8; dword 6 = xp stage)
#define OFF_VX  816   // x vector             (16)
#define OFF_VU  832   // u vector             (8)

__device__ __forceinline__ float dot15(const float* Lr, const float* v) {
    float4 x0 = *(const float4*)(Lr);
    float4 x1 = *(const float4*)(Lr + 4);
    float4 x2 = *(const float4*)(Lr + 8);
    float4 x3 = *(const float4*)(Lr + 12);
    return v[0]*x0.x + v[1]*x0.y + v[2]*x0.z + v[3]*x0.w
         + v[4]*x1.x + v[5]*x1.y + v[6]*x1.z + v[7]*x1.w
         + v[8]*x2.x + v[9]*x2.y + v[10]*x2.z + v[11]*x2.w
         + v[12]*x3.x + v[13]*x3.y + v[14]*x3.z;
}

__device__ __forceinline__ void axpy15(const float* Lr, float s, float* acc) {
    float4 x0 = *(const float4*)(Lr);
    float4 x1 = *(const float4*)(Lr + 4);
    float4 x2 = *(const float4*)(Lr + 8);
    float4 x3 = *(const float4*)(Lr + 12);
    acc[0]  += s*x0.x; acc[1]  += s*x0.y; acc[2]  += s*x0.z; acc[3]  += s*x0.w;
    acc[4]  += s*x1.x; acc[5]  += s*x1.y; acc[6]  += s*x1.z; acc[7]  += s*x1.w;
    acc[8]  += s*x2.x; acc[9]  += s*x2.y; acc[10] += s*x2.z; acc[11] += s*x2.w;
    acc[12] += s*x3.x; acc[13] += s*x3.y; acc[14] += s*x3.z;
}

__device__ __forceinline__ float dot6(const float* Lr, const float* v) {
    float4 x0 = *(const float4*)(Lr);
    float2 x1 = *(const float2*)(Lr + 4);
    return v[0]*x0.x + v[1]*x0.y + v[2]*x0.z + v[3]*x0.w + v[4]*x1.x + v[5]*x1.y;
}

__device__ __forceinline__ void wrow15(float* Lr, const float* v) {
    *(float4*)(Lr)      = make_float4(v[0], v[1], v[2], v[3]);
    *(float4*)(Lr + 4)  = make_float4(v[4], v[5], v[6], v[7]);
    *(float4*)(Lr + 8)  = make_float4(v[8], v[9], v[10], v[11]);
    *(float4*)(Lr + 12) = make_float4(v[12], v[13], v[14], 0.f);
}

__device__ __forceinline__ void wrow6(float* Lr, const float* v) {
    *(float4*)(Lr)     = make_float4(v[0], v[1], v[2], v[3]);
    *(float2*)(Lr + 4) = make_float2(v[4], v[5]);
}

__global__ __launch_bounds__(256, 3) void ekf_kernel(
    const float* __restrict__ g_state, const float* __restrict__ g_obs,
    const float* __restrict__ g_u,     const float* __restrict__ g_P,
    const float* __restrict__ g_A,     const float* __restrict__ g_B,
    const float* __restrict__ g_C,     const float* __restrict__ g_D,
    const float* __restrict__ g_c1,    const float* __restrict__ g_c2,
    const float* __restrict__ g_Q,     const float* __restrict__ g_R,
    float* __restrict__ o_xp, float* __restrict__ o_Pn, int bn)
{
    __shared__ __align__(16) float lds[16 * STR];
    const int tid  = threadIdx.x;
    const int ib0  = blockIdx.x * 16;
    const int nIt  = min(16, bn - ib0);

    const int g   = tid >> 4;
    const int r   = tid & 15;
    const int itc = ib0 + ((g < nIt) ? g : (nIt - 1));
    const int rc  = r < 15 ? r : 14;
    const int rc6 = r < 6 ? r : 5;
    float* L = lds + g * STR;

    // ---- per-lane small loads (prologue; short-lived regs) ----
    float b[6], q[6], rr[6];
    {
        const float* Bb = g_B + (size_t)itc * 90 + rc * 6;
        const float* Qb = g_Q + (size_t)itc * 36 + rc6 * 6;
        const float* Rb = g_R + (size_t)itc * 36 + rc6 * 6;
        #pragma unroll
        for (int j = 0; j < 6; ++j) { b[j] = Bb[j]; q[j] = Qb[j]; rr[j] = Rb[j]; }
    }
    float x    = g_state[(size_t)itc * 15 + rc];
    float uu   = g_u[(size_t)itc * 6 + rc6];
    float c1v  = g_c1[(size_t)itc * 15 + rc];
    float obsv = g_obs[(size_t)itc * 6 + rc6];
    float c2v  = g_c2[(size_t)itc * 6 + rc6];

    // ---- coalesced block staging: P -> M1, A -> M2, C -> CC ----
    {
        const float* gp = g_P + (size_t)ib0 * 225;
        const float* ga = g_A + (size_t)ib0 * 225;
        const int lim = nIt * 225;
        for (int i = tid; i < lim; i += 256) {
            int it = i / 225, idx = i - it * 225;
            int rw = idx / 15, j = idx - rw * 15;
            lds[it * STR + OFF_M1 + rw * 20 + j] = gp[i];
        }
        for (int i = tid; i < lim; i += 256) {
            int it = i / 225, idx = i - it * 225;
            int rw = idx / 15, j = idx - rw * 15;
            lds[it * STR + OFF_M2 + rw * 20 + j] = ga[i];
        }
        const float* gc = g_C + (size_t)ib0 * 90;
        const int limc = nIt * 90;
        for (int i = tid; i < limc; i += 256) {
            int it = i / 90, idx = i - it * 90;
            int rw = idx / 15, j = idx - rw * 15;
            lds[it * STR + OFF_C + rw * 16 + j] = gc[i];
        }
    }

    // stage per-lane vectors/rows
    if (r < 15) {
        wrow6(L + OFF_S4 + r * 8, b);    // B rows
        L[OFF_VX + r] = x;               // x vector
    }
    if (r == 15) L[OFF_VX + 15] = 0.f;
    if (r < 6)  L[OFF_VU + r] = uu;      // u vector

    __syncthreads();

    // ================= phase 1: xp0, ev =================
    float xp, ev;
    {
        // x vector (uniform)
        float xv[15];
        {
            const float* X = L + OFF_VX;
            float4 x0 = *(const float4*)(X);     float4 x1 = *(const float4*)(X + 4);
            float4 x2 = *(const float4*)(X + 8); float4 x3 = *(const float4*)(X + 12);
            xv[0]=x0.x; xv[1]=x0.y; xv[2]=x0.z; xv[3]=x0.w;
            xv[4]=x1.x; xv[5]=x1.y; xv[6]=x1.z; xv[7]=x1.w;
            xv[8]=x2.x; xv[9]=x2.y; xv[10]=x2.z; xv[11]=x2.w;
            xv[12]=x3.x; xv[13]=x3.y; xv[14]=x3.z;
        }
        // xp = A_row . x  (A row transient)
        xp = c1v + dot15(L + OFF_M2 + rc * 20, xv);
        // ev = obs - c2 - C_row . x  (C row transient)
        ev = obsv - c2v - dot15(L + OFF_C + rc6 * 16, xv);
        // u terms
        float u0_ = L[OFF_VU + 0], u1_ = L[OFF_VU + 1], u2_ = L[OFF_VU + 2];
        float u3_ = L[OFF_VU + 3], u4_ = L[OFF_VU + 4], u5_ = L[OFF_VU + 5];
        xp += b[0]*u0_ + b[1]*u1_ + b[2]*u2_ + b[3]*u3_ + b[4]*u4_ + b[5]*u5_;
        // D row loaded here (single use)
        const float* Db = g_D + (size_t)itc * 36 + rc6 * 6;
        ev -= Db[0]*u0_ + Db[1]*u1_ + Db[2]*u2_ + Db[3]*u3_ + Db[4]*u4_ + Db[5]*u5_;
    }

    // ================= phase 2: Pp = A P A^T + B Q B^T =================
    float pp[15];
    {
        // Y = A @ P : a scalars read from own A row (transient), P rows broadcast
        float y[15];
        #pragma unroll
        for (int j = 0; j < 15; ++j) y[j] = 0.f;
        {
            const float* Ar = L + OFF_M2 + rc * 20;
            #pragma unroll
            for (int k = 0; k < 15; ++k) axpy15(L + OFF_M1 + k * 20, Ar[k], y);
        }
        // Pp = Y @ A^T (A rows broadcast)
        #pragma unroll
        for (int j = 0; j < 15; ++j) pp[j] = dot15(L + OFF_M2 + j * 20, y);
    }
    {
        // Z = B @ Q (shuffles), Pp += Z @ B^T (B rows broadcast from S4)
        float z[6];
        #pragma unroll
        for (int j = 0; j < 6; ++j) z[j] = 0.f;
        #pragma unroll
        for (int k = 0; k < 6; ++k) {
            float bk = b[k];
            #pragma unroll
            for (int j = 0; j < 6; ++j) z[j] += bk * SHFL16(q[j], k);
        }
        #pragma unroll
        for (int j = 0; j < 15; ++j) pp[j] += dot6(L + OFF_S4 + j * 8, z);
    }

    // write Pp -> M1 (P dead)
    FENCE();
    if (r < 15) wrow15(L + OFF_M1 + r * 20, pp);
    FENCE();

    // ================= phase 3: K = Pp C^T inv(C Pp C^T + R) =================
    float ppct[6];
    #pragma unroll
    for (int j = 0; j < 6; ++j) ppct[j] = dot15(L + OFF_C + j * 16, pp);
    // pp dead

    FENCE();
    if (r < 15) wrow6(L + OFF_S4 + r * 8, ppct);   // PpCt -> S4 (B dead)
    FENCE();

    float sm[12];
    #pragma unroll
    for (int j = 0; j < 6; ++j) { sm[j] = rr[j]; sm[6 + j] = (r == j) ? 1.f : 0.f; }
    {
        const float* Cr = L + OFF_C + rc6 * 16;    // own C row, scalar re-reads
        #pragma unroll
        for (int k = 0; k < 15; ++k) {
            const float* Pk = L + OFF_S4 + k * 8;
            float4 v0 = *(const float4*)(Pk);
            float2 v1 = *(const float2*)(Pk + 4);
            float ck = Cr[k];
            sm[0] += ck * v0.x; sm[1] += ck * v0.y; sm[2] += ck * v0.z;
            sm[3] += ck * v0.w; sm[4] += ck * v1.x; sm[5] += ck * v1.y;
        }
    }
    // Gauss-Jordan invert S (SPD -> no pivoting)
    #pragma unroll
    for (int k = 0; k < 6; ++k) {
        float piv = SHFL16(sm[k], k);
        float ip  = 1.f / piv;
        float f   = sm[k];
        #pragma unroll
        for (int j = 0; j < 12; ++j) {
            float prj = SHFL16(sm[j], k) * ip;
            sm[j] = (r == k) ? prj : (sm[j] - f * prj);
        }
    }
    // K = PpCt @ Sinv (shuffles)
    float kk[6];
    #pragma unroll
    for (int j = 0; j < 6; ++j) kk[j] = 0.f;
    #pragma unroll
    for (int k = 0; k < 6; ++k) {
        float pk = ppct[k];
        #pragma unroll
        for (int j = 0; j < 6; ++j) kk[j] += pk * SHFL16(sm[6 + j], k);
    }
    // sm, ppct dead

    FENCE();
    if (r < 15) wrow6(L + OFF_S4 + r * 8, kk);     // K -> S4 (PpCt dead)
    FENCE();

    // xp += K e
    #pragma unroll
    for (int j = 0; j < 6; ++j) xp += kk[j] * SHFL16(ev, j);

    // ================= phase 4/5: Pn = IKC Pp IKC^T + K R K^T =================
    float pn[15];
    {
        float ikc[15];
        #pragma unroll
        for (int j = 0; j < 15; ++j) ikc[j] = (r == j) ? 1.f : 0.f;
        #pragma unroll
        for (int k = 0; k < 6; ++k) axpy15(L + OFF_C + k * 16, -kk[k], ikc);

        FENCE();
        if (r < 15) wrow15(L + OFF_M2 + r * 20, ikc);  // IKC -> M2 (A dead)
        FENCE();

        // T3 = IKC @ Pp
        float t3[15];
        #pragma unroll
        for (int j = 0; j < 15; ++j) t3[j] = 0.f;
        #pragma unroll
        for (int k = 0; k < 15; ++k) axpy15(L + OFF_M1 + k * 20, ikc[k], t3);
        // ikc regs dead

        // Pn = T3 @ IKC^T
        #pragma unroll
        for (int j = 0; j < 15; ++j) pn[j] = dot15(L + OFF_M2 + j * 20, t3);
    }
    {
        // KR = K @ R (shuffles), Pn += KR @ K^T (K rows broadcast)
        float kr[6];
        #pragma unroll
        for (int j = 0; j < 6; ++j) kr[j] = 0.f;
        #pragma unroll
        for (int k = 0; k < 6; ++k) {
            float kkk = kk[k];
            #pragma unroll
            for (int j = 0; j < 6; ++j) kr[j] += kkk * SHFL16(rr[j], k);
        }
        #pragma unroll
        for (int j = 0; j < 15; ++j) pn[j] += dot6(L + OFF_S4 + j * 8, kr);
    }

    // ---- stage results: Pn -> M1, xp -> S4 dword 6 ----
    FENCE();
    if (r < 15) {
        wrow15(L + OFF_M1 + r * 20, pn);
        L[OFF_S4 + r * 8 + 6] = xp;
    }
    __syncthreads();

    // ---- coalesced block stores ----
    {
        float* gpn = o_Pn + (size_t)ib0 * 225;
        const int lim = nIt * 225;
        for (int i = tid; i < lim; i += 256) {
            int it = i / 225, idx = i - it * 225;
            int rw = idx / 15, j = idx - rw * 15;
            gpn[i] = lds[it * STR + OFF_M1 + rw * 20 + j];
        }
        float* gxp = o_xp + (size_t)ib0 * 15;
        const int lim2 = nIt * 15;
        for (int i = tid; i < lim2; i += 256) {
            int it = i / 15, rw = i - it * 15;
            gxp[i] = lds[it * STR + OFF_S4 + rw * 8 + 6];
        }
    }
}

extern "C" void kernel_launch(void* const* d_in, const int* in_sizes, int n_in,
                              void* d_out, int out_size, void* d_ws, size_t ws_size,
                              hipStream_t stream) {
    const float* g_state = (const float*)d_in[0];
    const float* g_obs   = (const float*)d_in[1];
    const float* g_u     = (const float*)d_in[2];
    const float* g_P     = (const float*)d_in[3];
    const float* g_A     = (const float*)d_in[4];
    const float* g_B     = (const float*)d_in[5];
    const float* g_C     = (const float*)d_in[6];
    const float* g_D     = (const float*)d_in[7];
    const float* g_c1    = (const float*)d_in[8];
    const float* g_c2    = (const float*)d_in[9];
    const float* g_Q     = (const float*)d_in[10];
    const float* g_R     = (const float*)d_in[11];

    const int bn = in_sizes[0] / 15;
    float* o_xp = (float*)d_out;
    float* o_pn = o_xp + (size_t)bn * 15;

    const int blocks = (bn + 15) / 16;   // 16 items per 256-thread block
    ekf_kernel<<<blocks, 256, 0, stream>>>(
        g_state, g_obs, g_u, g_P, g_A, g_B, g_C, g_D, g_c1, g_c2, g_Q, g_R,
        o_xp, o_pn, bn);
}